// Round 5
// baseline (14172.160 us; speedup 1.0000x reference)
//
#include <hip/hip_runtime.h>
#include <cstdint>

typedef _Float16 f16;
using f16x2 = __attribute__((ext_vector_type(2))) _Float16;
using f16x4 = __attribute__((ext_vector_type(4))) _Float16;
using f16x8 = __attribute__((ext_vector_type(8))) _Float16;
using f32x4 = __attribute__((ext_vector_type(4))) float;
using u32x4 = __attribute__((ext_vector_type(4))) uint32_t;

__device__ __forceinline__ float sigmoidf_(float x) {
  float e = exp2f(-x * 1.44269504088896f);
  return 1.0f / (1.0f + e);
}
__device__ __forceinline__ float tanhf_(float x) {
  float e = exp2f(x * 2.88539008177793f);   // exp(2x)
  return 1.0f - 2.0f / (e + 1.0f);
}

// MFMA with B operand pinned in AGPR (no accvgpr_read round-trip) and the
// accumulator in AGPR. A (h broadcast) stays in VGPR.
__device__ __forceinline__ void mfma16_aa(f32x4& d, f16x8 a, u32x4 b) {
  asm("v_mfma_f32_16x16x32_f16 %0, %1, %2, %0"
      : "+a"(d)
      : "v"(a), "a"(b));
}

// ---------------- conversion / prep kernels ----------------

__global__ void f32_to_f16_kernel(const float* __restrict__ in, f16* __restrict__ out, long n4) {
  long stride = (long)gridDim.x * blockDim.x;
  for (long i = blockIdx.x * (long)blockDim.x + threadIdx.x; i < n4; i += stride) {
    f32x4 v = *(const f32x4*)(in + i * 4);
    f16x4 h;
    h[0] = (f16)v[0]; h[1] = (f16)v[1]; h[2] = (f16)v[2]; h[3] = (f16)v[3];
    *(f16x4*)(out + i * 4) = h;
  }
}

__global__ void addvec_kernel(const float* __restrict__ a, const float* __restrict__ b,
                              float* __restrict__ o, int n) {
  int i = blockIdx.x * blockDim.x + threadIdx.x;
  if (i < n) o[i] = a[i] + b[i];
}

__global__ void zero_u32_kernel(uint32_t* __restrict__ p, int n) {
  int i = blockIdx.x * blockDim.x + threadIdx.x;
  if (i < n) p[i] = 0;
}

// MFMA B-fragment weight prep.
// wp dword index i = ((t*8 + c)*64 + l)*4 + d  (t=tile<64, c=K-chunk<8, l=lane, d=dword<4)
// holds pack(W[t*16 + (l&15)][c*32 + ((l>>4)&3)*8 + 2d], W[same][.. + 2d + 1]).
__global__ void wprep_kernel(const float* __restrict__ whh, uint32_t* __restrict__ wp) {
  int i = blockIdx.x * blockDim.x + threadIdx.x;  // 131072 threads
  int d = i & 3, l = (i >> 2) & 63, c = (i >> 8) & 7, t = i >> 11;
  int r = t * 16 + (l & 15);
  int k0 = c * 32 + ((l >> 4) & 3) * 8 + 2 * d;
  float lo = whh[r * 256 + k0];
  float hi = whh[r * 256 + k0 + 1];
  f16x2 h;
  h[0] = (f16)lo; h[1] = (f16)hi;
  wp[i] = __builtin_bit_cast(uint32_t, h);
}

// ---------------- GEMM: C[m,n] = sum_k A[m,k]*B[n,k] + bias[n] ----------------
// A [M,K] f16 row-major, B [N,K] f16 row-major. 128x128 tile, BK=32, 256 thr.

template <int OUTF32>
__global__ __launch_bounds__(256) void gemm_bt_kernel(
    const f16* __restrict__ A, const f16* __restrict__ B,
    const float* __restrict__ bias, void* __restrict__ Cout,
    int M, int N, int K) {
  __shared__ __align__(16) f16 Al[128 * 32];
  __shared__ __align__(16) f16 Bl[128 * 32];
  const int tid = threadIdx.x;
  const int lane = tid & 63, wave = tid >> 6;
  const int bn = blockIdx.x, bm = blockIdx.y;
  const int qm = (wave >> 1) * 64, qn = (wave & 1) * 64;

  f32x4 acc[4][4];
#pragma unroll
  for (int i = 0; i < 4; ++i)
#pragma unroll
    for (int j = 0; j < 4; ++j) acc[i][j] = (f32x4){0.f, 0.f, 0.f, 0.f};

  const int c0 = tid, c1 = 256 + tid;
  const int row0 = c0 >> 2, off0 = c0 & 3;
  const int row1 = c1 >> 2, off1 = c1 & 3;
  const int gmA0 = min(bm * 128 + row0, M - 1);
  const int gmA1 = min(bm * 128 + row1, M - 1);
  const int gnB0 = min(bn * 128 + row0, N - 1);
  const int gnB1 = min(bn * 128 + row1, N - 1);

  for (int k0 = 0; k0 < K; k0 += 32) {
    u32x4 ar0 = *(const u32x4*)(A + (size_t)gmA0 * K + k0 + off0 * 8);
    u32x4 ar1 = *(const u32x4*)(A + (size_t)gmA1 * K + k0 + off1 * 8);
    u32x4 br0 = *(const u32x4*)(B + (size_t)gnB0 * K + k0 + off0 * 8);
    u32x4 br1 = *(const u32x4*)(B + (size_t)gnB1 * K + k0 + off1 * 8);
    __syncthreads();  // previous iteration's LDS reads done
    *(u32x4*)&Al[c0 * 8] = ar0;
    *(u32x4*)&Al[c1 * 8] = ar1;
    *(u32x4*)&Bl[c0 * 8] = br0;
    *(u32x4*)&Bl[c1 * 8] = br1;
    __syncthreads();
    f16x8 af[4], bf[4];
#pragma unroll
    for (int mt = 0; mt < 4; ++mt)
      af[mt] = *(const f16x8*)&Al[(qm + mt * 16 + (lane & 15)) * 32 + (lane >> 4) * 8];
#pragma unroll
    for (int nt = 0; nt < 4; ++nt)
      bf[nt] = *(const f16x8*)&Bl[(qn + nt * 16 + (lane & 15)) * 32 + (lane >> 4) * 8];
#pragma unroll
    for (int mt = 0; mt < 4; ++mt)
#pragma unroll
      for (int nt = 0; nt < 4; ++nt)
        acc[mt][nt] = __builtin_amdgcn_mfma_f32_16x16x32_f16(af[mt], bf[nt], acc[mt][nt], 0, 0, 0);
  }

#pragma unroll
  for (int mt = 0; mt < 4; ++mt)
#pragma unroll
    for (int nt = 0; nt < 4; ++nt)
#pragma unroll
      for (int j = 0; j < 4; ++j) {
        int gm = bm * 128 + qm + mt * 16 + (lane >> 4) * 4 + j;
        int gn = bn * 128 + qn + nt * 16 + (lane & 15);
        if (gm < M && gn < N) {
          float v = acc[mt][nt][j] + bias[gn];
          if (OUTF32)
            ((float*)Cout)[(size_t)gm * N + gn] = v;
          else
            ((f16*)Cout)[(size_t)gm * N + gn] = (f16)v;
        }
      }
}

// ---------------- persistent LSTM recurrence (pair-split, all-AGPR weights) ----------------
// 128 blocks: block = bb + 64*o, bb = batch, o = half (units o*128 .. o*128+127).
// 512 threads (8 waves). Wave w owns tiles {g*16 + o*8 + w : g=0..3} -> lane l&15
// holds ALL FOUR gates of unit u = o*128 + w*16 + (l&15) in 4 asm AGPR accumulators.
// All 32 weight tiles live in AGPRs (128 AGPR/wave), read directly by asm MFMA.
// Per step: own-half h from LDS hbuf (4 A-frag b128 reads), partner half from
// h_out global after a flag handshake (SYSTEM-scope atomics: release-publish after
// all h stores drained + barrier; relaxed poll + one acquire load -> L1/L2 inv so
// plain partner loads are fresh). Monotone step-counter flags, zeroed per launch.

__global__ __launch_bounds__(512, 2) void lstm_rec_kernel(
    const f16* __restrict__ xg,          // [B*T, 1024], biases included
    const u32x4* __restrict__ wp,        // [64 tiles][8 chunks][64 lanes] u32x4
    f16* __restrict__ h_all,             // [B*T, 256]
    uint32_t* __restrict__ flags,        // [128], zeroed before launch
    int T) {
  __shared__ __align__(16) f16 hbuf[2][128];     // own half, double-buffered
  const int bid = blockIdx.x;
  const int bb = bid & 63, o = bid >> 6, po = o ^ 1;
  const int tid = threadIdx.x;
  const int w = tid >> 6, lane = tid & 63;
  const int l15 = lane & 15, kg = (lane >> 4) & 3;
  const int u = o * 128 + w * 16 + l15;          // unit owned (dup x4 over kg)

  // all 4 gate tiles for this wave's units -> AGPR
  u32x4 wA[4][8];
#pragma unroll
  for (int g = 0; g < 4; ++g) {
    const int t = g * 16 + o * 8 + w;
#pragma unroll
    for (int c = 0; c < 8; ++c)
      wA[g][c] = wp[(t * 8 + c) * 64 + lane];
  }
  if (tid < 256) ((f16*)hbuf)[tid] = (f16)0.f;
  float cst = 0.f;
  __syncthreads();

  const f16* xt = xg + (size_t)bb * T * 1024;
  const uint32_t* pflag = &flags[bid ^ 64];
  uint32_t* myflag = &flags[bid];

  for (int t = 0; t < T; ++t) {
    // xg contributions for this step (L3/HBM latency hidden under MFMA phase)
    float xi = (float)xt[u], xf = (float)xt[u + 256];
    float xgv = (float)xt[u + 512], xo = (float)xt[u + 768];

    f32x4 z = (f32x4){0.f, 0.f, 0.f, 0.f};
    f32x4 aI = z, aF = z, aG = z, aO = z;       // AGPR accumulators
    // phase A: own-half K-chunks (global chunks o*4 .. o*4+3), A-frag from LDS
    const f16* hq = hbuf[t & 1];
#pragma unroll
    for (int cc = 0; cc < 4; ++cc) {
      f16x8 afr = *(const f16x8*)(hq + cc * 32 + kg * 8);
      mfma16_aa(aI, afr, wA[0][o * 4 + cc]);
      mfma16_aa(aF, afr, wA[1][o * 4 + cc]);
      mfma16_aa(aG, afr, wA[2][o * 4 + cc]);
      mfma16_aa(aO, afr, wA[3][o * 4 + cc]);
    }
    // phase B: partner half via flag handshake (h_out[t-1]); skipped at t=0 (h=0)
    if (t > 0) {
      while (__hip_atomic_load(pflag, __ATOMIC_RELAXED, __HIP_MEMORY_SCOPE_SYSTEM)
             < (uint32_t)t)
        __builtin_amdgcn_s_sleep(1);
      (void)__hip_atomic_load(pflag, __ATOMIC_ACQUIRE, __HIP_MEMORY_SCOPE_SYSTEM);
      __builtin_amdgcn_sched_barrier(0);
      const f16* ph = h_all + ((size_t)bb * T + (t - 1)) * 256 + po * 128;
      f16x8 p0 = *(const f16x8*)(ph + 0 * 32 + kg * 8);
      f16x8 p1 = *(const f16x8*)(ph + 1 * 32 + kg * 8);
      f16x8 p2 = *(const f16x8*)(ph + 2 * 32 + kg * 8);
      f16x8 p3 = *(const f16x8*)(ph + 3 * 32 + kg * 8);
      mfma16_aa(aI, p0, wA[0][po * 4 + 0]);
      mfma16_aa(aF, p0, wA[1][po * 4 + 0]);
      mfma16_aa(aG, p0, wA[2][po * 4 + 0]);
      mfma16_aa(aO, p0, wA[3][po * 4 + 0]);
      mfma16_aa(aI, p1, wA[0][po * 4 + 1]);
      mfma16_aa(aF, p1, wA[1][po * 4 + 1]);
      mfma16_aa(aG, p1, wA[2][po * 4 + 1]);
      mfma16_aa(aO, p1, wA[3][po * 4 + 1]);
      mfma16_aa(aI, p2, wA[0][po * 4 + 2]);
      mfma16_aa(aF, p2, wA[1][po * 4 + 2]);
      mfma16_aa(aG, p2, wA[2][po * 4 + 2]);
      mfma16_aa(aO, p2, wA[3][po * 4 + 2]);
      mfma16_aa(aI, p3, wA[0][po * 4 + 3]);
      mfma16_aa(aF, p3, wA[1][po * 4 + 3]);
      mfma16_aa(aG, p3, wA[2][po * 4 + 3]);
      mfma16_aa(aO, p3, wA[3][po * 4 + 3]);
    }
    // activation (accvgpr_read of element 0; rows duplicated so any j works)
    float iv = sigmoidf_(aI[0] + xi);
    float fv = sigmoidf_(aF[0] + xf);
    float gv = tanhf_(aG[0] + xgv);
    float ov = sigmoidf_(aO[0] + xo);
    cst = fv * cst + iv * gv;
    float hval = ov * tanhf_(cst);
    f16 hh = (f16)hval;
    // publish h: LDS (own next-step reads) + global (partner + next layer)
    if (lane < 16) hbuf[(t + 1) & 1][w * 16 + l15] = hh;
    int hb = (int)__builtin_bit_cast(uint16_t, hh);
    int plo = __shfl(hb, (lane & 7) * 2, 64);
    int phi = __shfl(hb, (lane & 7) * 2 + 1, 64);
    if (lane < 8) {
      uint32_t pk = ((uint32_t)plo & 0xffffu) | ((uint32_t)phi << 16);
      uint32_t* hrow = (uint32_t*)(h_all + ((size_t)bb * T + t) * 256 + o * 128);
      __hip_atomic_store(hrow + w * 8 + lane, pk, __ATOMIC_RELAXED,
                         __HIP_MEMORY_SCOPE_SYSTEM);
    }
    xt += 1024;
    asm volatile("s_waitcnt vmcnt(0) lgkmcnt(0)" ::: "memory");
    __builtin_amdgcn_s_barrier();
    if (tid == 0)
      __hip_atomic_store(myflag, (uint32_t)(t + 1), __ATOMIC_RELEASE,
                         __HIP_MEMORY_SCOPE_SYSTEM);
    __builtin_amdgcn_sched_barrier(0);
  }
}

// ---------------- fused LayerNorm + attention pooling ----------------
// one block per batch, 256 threads.

__global__ __launch_bounds__(256) void ln_attn_kernel(
    const f16* __restrict__ h2, const float* __restrict__ lnw,
    const float* __restrict__ lnb, const float* __restrict__ aw,
    f16* __restrict__ att_out) {
  const int b = blockIdx.x, tid = threadIdx.x;
  const int lane = tid & 63, wave = tid >> 6;
  __shared__ float smu[512], sis[512], ssc[512];
  __shared__ float vbuf[256];
  __shared__ float red[16];

  float vj = aw[tid] * lnw[tid];
  float uj = aw[tid] * lnb[tid];
  vbuf[tid] = vj;
  float rv = vj, ru = uj;
#pragma unroll
  for (int m = 1; m < 64; m <<= 1) { rv += __shfl_xor(rv, m, 64); ru += __shfl_xor(ru, m, 64); }
  if (lane == 0) { red[wave] = rv; red[4 + wave] = ru; }
  __syncthreads();
  const float Vsum = red[0] + red[1] + red[2] + red[3];
  const float Csum = red[4] + red[5] + red[6] + red[7];
  const f32x4 v4 = *(const f32x4*)&vbuf[lane * 4];
  const f16* hb = h2 + (size_t)b * 512 * 256;

  for (int tt = wave; tt < 512; tt += 4) {
    f16x4 hv = *(const f16x4*)(hb + (size_t)tt * 256 + lane * 4);
    float h0 = (float)hv[0], h1 = (float)hv[1], h2v = (float)hv[2], h3 = (float)hv[3];
    float s1 = h0 + h1 + h2v + h3;
    float s2 = h0 * h0 + h1 * h1 + h2v * h2v + h3 * h3;
    float sv = h0 * v4[0] + h1 * v4[1] + h2v * v4[2] + h3 * v4[3];
#pragma unroll
    for (int m = 1; m < 64; m <<= 1) {
      s1 += __shfl_xor(s1, m, 64);
      s2 += __shfl_xor(s2, m, 64);
      sv += __shfl_xor(sv, m, 64);
    }
    if (lane == 0) {
      float mu = s1 * (1.0f / 256.0f);
      float var = s2 * (1.0f / 256.0f) - mu * mu;
      float is = rsqrtf(var + 1e-5f);
      smu[tt] = mu; sis[tt] = is;
      ssc[tt] = (sv - mu * Vsum) * is + Csum;
    }
  }
  __syncthreads();
  // softmax over 512 scores
  float a0 = ssc[tid], a1 = ssc[tid + 256];
  float mx = fmaxf(a0, a1);
#pragma unroll
  for (int m = 1; m < 64; m <<= 1) mx = fmaxf(mx, __shfl_xor(mx, m, 64));
  if (lane == 0) red[wave] = mx;
  __syncthreads();
  mx = fmaxf(fmaxf(red[0], red[1]), fmaxf(red[2], red[3]));
  __syncthreads();  // protect red reuse
  float p0 = exp2f((a0 - mx) * 1.44269504f);
  float p1 = exp2f((a1 - mx) * 1.44269504f);
  float ps = p0 + p1;
  float pm = p0 * smu[tid] * sis[tid] + p1 * smu[tid + 256] * sis[tid + 256];
#pragma unroll
  for (int m = 1; m < 64; m <<= 1) { ps += __shfl_xor(ps, m, 64); pm += __shfl_xor(pm, m, 64); }
  if (lane == 0) { red[wave] = ps; red[8 + wave] = pm; }
  __syncthreads();
  const float S = red[0] + red[1] + red[2] + red[3];
  const float PM = (red[8] + red[9] + red[10] + red[11]) / S;
  ssc[tid] = p0 / S * sis[tid];          // alpha_t
  ssc[tid + 256] = p1 / S * sis[tid + 256];
  __syncthreads();
  // pass 2: attended_j = lnw_j*(sum_t alpha_t h_tj - PM) + lnb_j
  float acc = 0.f;
  for (int t = 0; t < 512; ++t) acc += ssc[t] * (float)hb[(size_t)t * 256 + tid];
  float att = lnw[tid] * (acc - PM) + lnb[tid];
  att_out[b * 256 + tid] = (f16)att;
}

// ---------------- launch ----------------

extern "C" void kernel_launch(void* const* d_in, const int* in_sizes, int n_in,
                              void* d_out, int out_size, void* d_ws, size_t ws_size,
                              hipStream_t stream) {
  (void)in_sizes; (void)n_in; (void)out_size; (void)ws_size;
  const float* x    = (const float*)d_in[0];
  const float* wih0 = (const float*)d_in[1];
  const float* whh0 = (const float*)d_in[2];
  const float* bih0 = (const float*)d_in[3];
  const float* bhh0 = (const float*)d_in[4];
  const float* wih1 = (const float*)d_in[5];
  const float* whh1 = (const float*)d_in[6];
  const float* bih1 = (const float*)d_in[7];
  const float* bhh1 = (const float*)d_in[8];
  const float* lnw  = (const float*)d_in[9];
  const float* lnb  = (const float*)d_in[10];
  const float* aw   = (const float*)d_in[11];
  const float* fcw  = (const float*)d_in[12];
  const float* fcb  = (const float*)d_in[13];

  char* ws = (char*)d_ws;
  f16* x_h      = (f16*)(ws + 0);            // 50331648 B; region reused after GEMM0:
  f16* h1       = (f16*)(ws + 0);            //   h1: 16777216 B
  f16* h2       = (f16*)(ws + 16777216);     //   h2: 16777216 B
  uint32_t* flg = (uint32_t*)(ws + 33554432);//   flags: 1024 B (dead x_h space)
  f16* wih0_h   = (f16*)(ws + 50331648);     // 1572864
  f16* wih1_h   = (f16*)(ws + 51904512);     // 524288
  f16* fcw_h    = (f16*)(ws + 52428800);     // 15627264
  uint32_t* wp0 = (uint32_t*)(ws + 68056064);// 524288
  uint32_t* wp1 = (uint32_t*)(ws + 68580352);// 524288
  float* bsum0  = (float*)(ws + 69104640);   // 4096
  float* bsum1  = (float*)(ws + 69108736);   // 4096
  f16* att_h    = (f16*)(ws + 69112832);     // 32768
  f16* xg       = (f16*)(ws + 69145600);     // 67108864 (shared by both layers)

  f32_to_f16_kernel<<<4096, 256, 0, stream>>>(x, x_h, 25165824 / 4);
  f32_to_f16_kernel<<<768, 256, 0, stream>>>(wih0, wih0_h, 786432 / 4);
  f32_to_f16_kernel<<<256, 256, 0, stream>>>(wih1, wih1_h, 262144 / 4);
  f32_to_f16_kernel<<<2048, 256, 0, stream>>>(fcw, fcw_h, 7813632 / 4);
  addvec_kernel<<<4, 256, 0, stream>>>(bih0, bhh0, bsum0, 1024);
  addvec_kernel<<<4, 256, 0, stream>>>(bih1, bhh1, bsum1, 1024);
  wprep_kernel<<<512, 256, 0, stream>>>(whh0, wp0);
  wprep_kernel<<<512, 256, 0, stream>>>(whh1, wp1);

  // layer 0: xg0 = x @ w_ih0^T + (b_ih0 + b_hh0)
  gemm_bt_kernel<0><<<dim3(8, 256), 256, 0, stream>>>(x_h, wih0_h, bsum0, xg, 32768, 1024, 768);
  // x_h now dead; zero the pair-sync flags living in its tail
  zero_u32_kernel<<<1, 256, 0, stream>>>(flg, 256);
  lstm_rec_kernel<<<128, 512, 0, stream>>>(xg, (const u32x4*)wp0, h1, flg, 512);
  // layer 1
  gemm_bt_kernel<0><<<dim3(8, 256), 256, 0, stream>>>(h1, wih1_h, bsum1, xg, 32768, 1024, 256);
  lstm_rec_kernel<<<128, 512, 0, stream>>>(xg, (const u32x4*)wp1, h2, flg + 128, 512);
  // LN + attention pooling
  ln_attn_kernel<<<64, 256, 0, stream>>>(h2, lnw, lnb, aw, att_h);
  // FC: out = attended @ fc_w^T + fc_b  (fp32 out)
  gemm_bt_kernel<1><<<dim3(239, 1), 256, 0, stream>>>(att_h, fcw_h, fcb, d_out, 64, 30522, 256);
}

// Round 7
// 2212.360 us; speedup vs baseline: 6.4059x; 6.4059x over previous
//
#include <hip/hip_runtime.h>
#include <cstdint>

typedef _Float16 f16;
using f16x2 = __attribute__((ext_vector_type(2))) _Float16;
using f16x4 = __attribute__((ext_vector_type(4))) _Float16;
using f16x8 = __attribute__((ext_vector_type(8))) _Float16;
using f32x4 = __attribute__((ext_vector_type(4))) float;
using u32x4 = __attribute__((ext_vector_type(4))) uint32_t;
using i32x4 = __attribute__((ext_vector_type(4))) int;

__device__ __forceinline__ float sigmoidf_(float x) {
  float e = exp2f(-x * 1.44269504088896f);
  return 1.0f / (1.0f + e);
}
__device__ __forceinline__ float tanhf_(float x) {
  float e = exp2f(x * 2.88539008177793f);   // exp(2x)
  return 1.0f - 2.0f / (e + 1.0f);
}

// i8 MFMA, B operand + accumulator pinned in AGPR (zero-move weight reads).
__device__ __forceinline__ void mfma_i8(i32x4& d, u32x4 a, u32x4 b) {
  asm("v_mfma_i32_16x16x64_i8 %0, %1, %2, %0"
      : "+a"(d)
      : "v"(a), "a"(b));
}

// ---------------- conversion / prep kernels ----------------

__global__ void f32_to_f16_kernel(const float* __restrict__ in, f16* __restrict__ out, long n4) {
  long stride = (long)gridDim.x * blockDim.x;
  for (long i = blockIdx.x * (long)blockDim.x + threadIdx.x; i < n4; i += stride) {
    f32x4 v = *(const f32x4*)(in + i * 4);
    f16x4 h;
    h[0] = (f16)v[0]; h[1] = (f16)v[1]; h[2] = (f16)v[2]; h[3] = (f16)v[3];
    *(f16x4*)(out + i * 4) = h;
  }
}

__global__ void addvec_kernel(const float* __restrict__ a, const float* __restrict__ b,
                              float* __restrict__ o, int n) {
  int i = blockIdx.x * blockDim.x + threadIdx.x;
  if (i < n) o[i] = a[i] + b[i];
}

// Per-gate-row symmetric int8 scales: qmul[r]=127/max|W_r|, dmul[r]=max|W_r|/127^2.
__global__ __launch_bounds__(256) void rowscale_kernel(const float* __restrict__ whh,
                                                       float* __restrict__ qmul,
                                                       float* __restrict__ dmul) {
  const int wv = (blockIdx.x * 256 + threadIdx.x) >> 6;  // global wave 0..63
  const int lane = threadIdx.x & 63;
  for (int rr = 0; rr < 16; ++rr) {
    int r = wv * 16 + rr;
    f32x4 v = *(const f32x4*)(whh + r * 256 + lane * 4);
    float m = fmaxf(fmaxf(fabsf(v[0]), fabsf(v[1])), fmaxf(fabsf(v[2]), fabsf(v[3])));
#pragma unroll
    for (int s = 1; s < 64; s <<= 1) m = fmaxf(m, __shfl_xor(m, s, 64));
    if (lane == 0) {
      float sr = fmaxf(m, 1e-8f);
      qmul[r] = 127.0f / sr;
      dmul[r] = sr / 16129.0f;
    }
  }
}

// int8 B-fragment prep for v_mfma_i32_16x16x64_i8.
// dword i = ((t*4 + c)*64 + l)*4 + d ; byte e of dword holds
// Wq[r = t*16 + (l&15)][k = c*64 + ((l>>4)&3)*16 + d*4 + e].
// (A-side h8 packing uses the same (lane,byte)->k map; contraction is
// invariant to the shared permutation, so this is correct by construction.)
__global__ void wq8_kernel(const float* __restrict__ whh, const float* __restrict__ qmul,
                           uint32_t* __restrict__ wq) {
  int i = blockIdx.x * blockDim.x + threadIdx.x;  // 65536 threads
  int d = i & 3, l = (i >> 2) & 63, c = (i >> 8) & 3, t = i >> 10;
  int r = t * 16 + (l & 15);
  int k0 = c * 64 + ((l >> 4) & 3) * 16 + d * 4;
  float qm = qmul[r];
  uint32_t out = 0;
#pragma unroll
  for (int e = 0; e < 4; ++e) {
    int q = __float2int_rn(whh[r * 256 + k0 + e] * qm);
    q = min(127, max(-127, q));
    out |= ((uint32_t)(uint8_t)(int8_t)q) << (8 * e);
  }
  wq[i] = out;
}

// ---------------- GEMM: C[m,n] = sum_k A[m,k]*B[n,k] + bias[n] ----------------
// A [M,K] f16 row-major, B [N,K] f16 row-major. 128x128 tile, BK=32, 256 thr.

template <int OUTF32>
__global__ __launch_bounds__(256) void gemm_bt_kernel(
    const f16* __restrict__ A, const f16* __restrict__ B,
    const float* __restrict__ bias, void* __restrict__ Cout,
    int M, int N, int K) {
  __shared__ __align__(16) f16 Al[128 * 32];
  __shared__ __align__(16) f16 Bl[128 * 32];
  const int tid = threadIdx.x;
  const int lane = tid & 63, wave = tid >> 6;
  const int bn = blockIdx.x, bm = blockIdx.y;
  const int qm = (wave >> 1) * 64, qn = (wave & 1) * 64;

  f32x4 acc[4][4];
#pragma unroll
  for (int i = 0; i < 4; ++i)
#pragma unroll
    for (int j = 0; j < 4; ++j) acc[i][j] = (f32x4){0.f, 0.f, 0.f, 0.f};

  const int c0 = tid, c1 = 256 + tid;
  const int row0 = c0 >> 2, off0 = c0 & 3;
  const int row1 = c1 >> 2, off1 = c1 & 3;
  const int gmA0 = min(bm * 128 + row0, M - 1);
  const int gmA1 = min(bm * 128 + row1, M - 1);
  const int gnB0 = min(bn * 128 + row0, N - 1);
  const int gnB1 = min(bn * 128 + row1, N - 1);

  for (int k0 = 0; k0 < K; k0 += 32) {
    u32x4 ar0 = *(const u32x4*)(A + (size_t)gmA0 * K + k0 + off0 * 8);
    u32x4 ar1 = *(const u32x4*)(A + (size_t)gmA1 * K + k0 + off1 * 8);
    u32x4 br0 = *(const u32x4*)(B + (size_t)gnB0 * K + k0 + off0 * 8);
    u32x4 br1 = *(const u32x4*)(B + (size_t)gnB1 * K + k0 + off1 * 8);
    __syncthreads();  // previous iteration's LDS reads done
    *(u32x4*)&Al[c0 * 8] = ar0;
    *(u32x4*)&Al[c1 * 8] = ar1;
    *(u32x4*)&Bl[c0 * 8] = br0;
    *(u32x4*)&Bl[c1 * 8] = br1;
    __syncthreads();
    f16x8 af[4], bf[4];
#pragma unroll
    for (int mt = 0; mt < 4; ++mt)
      af[mt] = *(const f16x8*)&Al[(qm + mt * 16 + (lane & 15)) * 32 + (lane >> 4) * 8];
#pragma unroll
    for (int nt = 0; nt < 4; ++nt)
      bf[nt] = *(const f16x8*)&Bl[(qn + nt * 16 + (lane & 15)) * 32 + (lane >> 4) * 8];
#pragma unroll
    for (int mt = 0; mt < 4; ++mt)
#pragma unroll
      for (int nt = 0; nt < 4; ++nt)
        acc[mt][nt] = __builtin_amdgcn_mfma_f32_16x16x32_f16(af[mt], bf[nt], acc[mt][nt], 0, 0, 0);
  }

#pragma unroll
  for (int mt = 0; mt < 4; ++mt)
#pragma unroll
    for (int nt = 0; nt < 4; ++nt)
#pragma unroll
      for (int j = 0; j < 4; ++j) {
        int gm = bm * 128 + qm + mt * 16 + (lane >> 4) * 4 + j;
        int gn = bn * 128 + qn + nt * 16 + (lane & 15);
        if (gm < M && gn < N) {
          float v = acc[mt][nt][j] + bias[gn];
          if (OUTF32)
            ((float*)Cout)[(size_t)gm * N + gn] = v;
          else
            ((f16*)Cout)[(size_t)gm * N + gn] = (f16)v;
        }
      }
}

// ---------------- persistent LSTM recurrence (int8 MFMA, two-level h) ----------------
// 64 blocks (1 batch) x 512 threads (8 waves), __launch_bounds__(512,2).
// v_mfma_i32_16x16x64_i8, ALL 64 weight tiles (256 KB) in AGPRs (8 tiles/wave x 16
// regs = 128 AGPR + 8 acc = 160). TWO-LEVEL h in the A operand's rows (free):
//   A row 0 = h_hi (int8, h*127), A row 1 = h_lo (int8 residual, h*16129 - 127*hi),
//   rows 2-15 read the hi slice (benign copies). Same MFMA computes BOTH matvecs:
//   D row 0 = Wq . h_hi, D row 1 = Wq . h_lo (C/D map: col=lane&15, row=(lane>>4)*4+reg
//   [m89-verified]), so kg=0 lanes hold both in acc regs 0,1.
// gate = dmul*D_hi + (dmul/127)*D_lo + xg  -> h precision 1/16129 (abs err 3e-5),
// killing the absolute-error compounding that sank the 1-level int8 run.
// Per step: 4 ds_read_b128 A-frags + 32 asm MFMAs, zero weight loads, 1 barrier.

__global__ __launch_bounds__(512, 2) void lstm_rec_kernel(
    const f16* __restrict__ xg,          // [B*T, 1024], biases included
    const u32x4* __restrict__ wq,        // [64 t][4 c][64 l] u32x4 int8 frags
    const float* __restrict__ dmul,      // [1024] per-row dequant scale
    f16* __restrict__ h_out,             // [B*T, 256]
    int T) {
  __shared__ __align__(16) uint8_t h8[2][512];   // [hi 256 | lo 256], double-buffered
  const int b = blockIdx.x;
  const int tid = threadIdx.x;
  const int w = tid >> 6, lane = tid & 63;
  const int l15 = lane & 15, kg = (lane >> 4) & 3;
  const int base = w * 16 + l15;        // row(j) = base + 128*j ; uA=base, uB=base+128
  const int uA = base, uB = base + 128;
  const int asel = (l15 == 1) ? 256 : 0;  // row1 lanes read the lo slice

  // all 8 tiles -> AGPR (used only via "a" asm operands)
  u32x4 wt[8][4];
#pragma unroll
  for (int j = 0; j < 8; ++j)
#pragma unroll
    for (int c = 0; c < 4; ++c)
      wt[j][c] = wq[((w + 8 * j) * 4 + c) * 64 + lane];
  float sc[8], sc2[8];
#pragma unroll
  for (int j = 0; j < 8; ++j) {
    sc[j] = dmul[base + 128 * j];
    sc2[j] = sc[j] * (1.0f / 127.0f);
  }

  if (tid < 256) ((uint32_t*)h8)[tid] = 0;   // zero both buffers (1 KB)
  float cA = 0.f, cB = 0.f;
  __syncthreads();

  const f16* xt = xg + (size_t)b * T * 1024;
  f16* hob = h_out + (size_t)b * T * 256;

  for (int t = 0; t < T; ++t) {
    // xg contributions (issued early; consumed after MFMA phase -> latency hidden)
    float xv0 = (float)xt[base];
    float xv1 = (float)xt[base + 128];
    float xv2 = (float)xt[base + 256];
    float xv3 = (float)xt[base + 384];
    float xv4 = (float)xt[base + 512];
    float xv5 = (float)xt[base + 640];
    float xv6 = (float)xt[base + 768];
    float xv7 = (float)xt[base + 896];

    i32x4 z = (i32x4){0, 0, 0, 0};
    i32x4 a0 = z, a1 = z, a2 = z, a3 = z, a4 = z, a5 = z, a6 = z, a7 = z;
    const uint8_t* hq = h8[t & 1] + asel;
#pragma unroll
    for (int c = 0; c < 4; ++c) {
      u32x4 afr = *(const u32x4*)(hq + c * 64 + kg * 16);   // row0=hi, row1=lo
      mfma_i8(a0, afr, wt[0][c]);
      mfma_i8(a1, afr, wt[1][c]);
      mfma_i8(a2, afr, wt[2][c]);
      mfma_i8(a3, afr, wt[3][c]);
      mfma_i8(a4, afr, wt[4][c]);
      mfma_i8(a5, afr, wt[5][c]);
      mfma_i8(a6, afr, wt[6][c]);
      mfma_i8(a7, afr, wt[7][c]);
    }
    // dequant + activation (valid on kg=0 lanes; others compute discarded garbage)
    float gI_A = (float)a0[0] * sc[0] + (float)a0[1] * sc2[0] + xv0;
    float gI_B = (float)a1[0] * sc[1] + (float)a1[1] * sc2[1] + xv1;
    float gF_A = (float)a2[0] * sc[2] + (float)a2[1] * sc2[2] + xv2;
    float gF_B = (float)a3[0] * sc[3] + (float)a3[1] * sc2[3] + xv3;
    float gG_A = (float)a4[0] * sc[4] + (float)a4[1] * sc2[4] + xv4;
    float gG_B = (float)a5[0] * sc[5] + (float)a5[1] * sc2[5] + xv5;
    float gO_A = (float)a6[0] * sc[6] + (float)a6[1] * sc2[6] + xv6;
    float gO_B = (float)a7[0] * sc[7] + (float)a7[1] * sc2[7] + xv7;
    float iA = sigmoidf_(gI_A), iB = sigmoidf_(gI_B);
    float fA = sigmoidf_(gF_A), fB = sigmoidf_(gF_B);
    float gA = tanhf_(gG_A),   gB = tanhf_(gG_B);
    float oA = sigmoidf_(gO_A), oB = sigmoidf_(gO_B);
    cA = fA * cA + iA * gA;
    cB = fB * cB + iB * gB;
    float hA = oA * tanhf_(cA);
    float hB = oB * tanhf_(cB);
    // two-level quantize: hi = round(h*127); lo = round((h - hi/127)*16129)
    int hiA = __float2int_rn(hA * 127.0f);
    int hiB = __float2int_rn(hB * 127.0f);
    int loA = __float2int_rn(fmaf((float)hiA, -127.0f, hA * 16129.0f));
    int loB = __float2int_rn(fmaf((float)hiB, -127.0f, hB * 16129.0f));
    uint8_t* hn = (uint8_t*)h8[(t + 1) & 1];
    if (lane < 16) {
      hn[uA] = (uint8_t)(int8_t)hiA;
      hn[uB] = (uint8_t)(int8_t)hiB;
      hn[256 + uA] = (uint8_t)(int8_t)loA;
      hn[256 + uB] = (uint8_t)(int8_t)loB;
      hob[(size_t)t * 256 + uA] = (f16)hA;   // global h (vmcnt floats, never drained)
      hob[(size_t)t * 256 + uB] = (f16)hB;
    }
    xt += 1024;
    asm volatile("s_waitcnt lgkmcnt(0)" ::: "memory");  // h8 writes visible
    __builtin_amdgcn_s_barrier();
    __builtin_amdgcn_sched_barrier(0);
  }
}

// ---------------- fused LayerNorm + attention pooling ----------------
// one block per batch, 256 threads.

__global__ __launch_bounds__(256) void ln_attn_kernel(
    const f16* __restrict__ h2, const float* __restrict__ lnw,
    const float* __restrict__ lnb, const float* __restrict__ aw,
    f16* __restrict__ att_out) {
  const int b = blockIdx.x, tid = threadIdx.x;
  const int lane = tid & 63, wave = tid >> 6;
  __shared__ float smu[512], sis[512], ssc[512];
  __shared__ float vbuf[256];
  __shared__ float red[16];

  float vj = aw[tid] * lnw[tid];
  float uj = aw[tid] * lnb[tid];
  vbuf[tid] = vj;
  float rv = vj, ru = uj;
#pragma unroll
  for (int m = 1; m < 64; m <<= 1) { rv += __shfl_xor(rv, m, 64); ru += __shfl_xor(ru, m, 64); }
  if (lane == 0) { red[wave] = rv; red[4 + wave] = ru; }
  __syncthreads();
  const float Vsum = red[0] + red[1] + red[2] + red[3];
  const float Csum = red[4] + red[5] + red[6] + red[7];
  const f32x4 v4 = *(const f32x4*)&vbuf[lane * 4];
  const f16* hb = h2 + (size_t)b * 512 * 256;

  for (int tt = wave; tt < 512; tt += 4) {
    f16x4 hv = *(const f16x4*)(hb + (size_t)tt * 256 + lane * 4);
    float h0 = (float)hv[0], h1 = (float)hv[1], h2v = (float)hv[2], h3 = (float)hv[3];
    float s1 = h0 + h1 + h2v + h3;
    float s2 = h0 * h0 + h1 * h1 + h2v * h2v + h3 * h3;
    float sv = h0 * v4[0] + h1 * v4[1] + h2v * v4[2] + h3 * v4[3];
#pragma unroll
    for (int m = 1; m < 64; m <<= 1) {
      s1 += __shfl_xor(s1, m, 64);
      s2 += __shfl_xor(s2, m, 64);
      sv += __shfl_xor(sv, m, 64);
    }
    if (lane == 0) {
      float mu = s1 * (1.0f / 256.0f);
      float var = s2 * (1.0f / 256.0f) - mu * mu;
      float is = rsqrtf(var + 1e-5f);
      smu[tt] = mu; sis[tt] = is;
      ssc[tt] = (sv - mu * Vsum) * is + Csum;
    }
  }
  __syncthreads();
  // softmax over 512 scores
  float a0 = ssc[tid], a1 = ssc[tid + 256];
  float mx = fmaxf(a0, a1);
#pragma unroll
  for (int m = 1; m < 64; m <<= 1) mx = fmaxf(mx, __shfl_xor(mx, m, 64));
  if (lane == 0) red[wave] = mx;
  __syncthreads();
  mx = fmaxf(fmaxf(red[0], red[1]), fmaxf(red[2], red[3]));
  __syncthreads();  // protect red reuse
  float p0 = exp2f((a0 - mx) * 1.44269504f);
  float p1 = exp2f((a1 - mx) * 1.44269504f);
  float ps = p0 + p1;
  float pm = p0 * smu[tid] * sis[tid] + p1 * smu[tid + 256] * sis[tid + 256];
#pragma unroll
  for (int m = 1; m < 64; m <<= 1) { ps += __shfl_xor(ps, m, 64); pm += __shfl_xor(pm, m, 64); }
  if (lane == 0) { red[wave] = ps; red[8 + wave] = pm; }
  __syncthreads();
  const float S = red[0] + red[1] + red[2] + red[3];
  const float PM = (red[8] + red[9] + red[10] + red[11]) / S;
  ssc[tid] = p0 / S * sis[tid];          // alpha_t
  ssc[tid + 256] = p1 / S * sis[tid + 256];
  __syncthreads();
  // pass 2: attended_j = lnw_j*(sum_t alpha_t h_tj - PM) + lnb_j
  float acc = 0.f;
  for (int t = 0; t < 512; ++t) acc += ssc[t] * (float)hb[(size_t)t * 256 + tid];
  float att = lnw[tid] * (acc - PM) + lnb[tid];
  att_out[b * 256 + tid] = (f16)att;
}

// ---------------- launch ----------------

extern "C" void kernel_launch(void* const* d_in, const int* in_sizes, int n_in,
                              void* d_out, int out_size, void* d_ws, size_t ws_size,
                              hipStream_t stream) {
  (void)in_sizes; (void)n_in; (void)out_size; (void)ws_size;
  const float* x    = (const float*)d_in[0];
  const float* wih0 = (const float*)d_in[1];
  const float* whh0 = (const float*)d_in[2];
  const float* bih0 = (const float*)d_in[3];
  const float* bhh0 = (const float*)d_in[4];
  const float* wih1 = (const float*)d_in[5];
  const float* whh1 = (const float*)d_in[6];
  const float* bih1 = (const float*)d_in[7];
  const float* bhh1 = (const float*)d_in[8];
  const float* lnw  = (const float*)d_in[9];
  const float* lnb  = (const float*)d_in[10];
  const float* aw   = (const float*)d_in[11];
  const float* fcw  = (const float*)d_in[12];
  const float* fcb  = (const float*)d_in[13];

  char* ws = (char*)d_ws;
  f16* x_h      = (f16*)(ws + 0);            // 50331648 B; region reused after GEMM0:
  f16* h1       = (f16*)(ws + 0);            //   h1: 16777216 B
  f16* h2       = (f16*)(ws + 16777216);     //   h2: 16777216 B
  f16* wih0_h   = (f16*)(ws + 50331648);     // 1572864
  f16* wih1_h   = (f16*)(ws + 51904512);     // 524288
  f16* fcw_h    = (f16*)(ws + 52428800);     // 15627264
  uint32_t* wq0 = (uint32_t*)(ws + 68056064);// 262144
  uint32_t* wq1 = (uint32_t*)(ws + 68318208);// 262144
  float* qmul0  = (float*)(ws + 68580352);   // 4096
  float* dmul0  = (float*)(ws + 68584448);   // 4096
  float* qmul1  = (float*)(ws + 68588544);   // 4096
  float* dmul1  = (float*)(ws + 68592640);   // 4096
  float* bsum0  = (float*)(ws + 69104640);   // 4096
  float* bsum1  = (float*)(ws + 69108736);   // 4096
  f16* att_h    = (f16*)(ws + 69112832);     // 32768
  f16* xg       = (f16*)(ws + 69145600);     // 67108864 (shared by both layers)

  f32_to_f16_kernel<<<4096, 256, 0, stream>>>(x, x_h, 25165824 / 4);
  f32_to_f16_kernel<<<768, 256, 0, stream>>>(wih0, wih0_h, 786432 / 4);
  f32_to_f16_kernel<<<256, 256, 0, stream>>>(wih1, wih1_h, 262144 / 4);
  f32_to_f16_kernel<<<2048, 256, 0, stream>>>(fcw, fcw_h, 7813632 / 4);
  addvec_kernel<<<4, 256, 0, stream>>>(bih0, bhh0, bsum0, 1024);
  addvec_kernel<<<4, 256, 0, stream>>>(bih1, bhh1, bsum1, 1024);
  rowscale_kernel<<<16, 256, 0, stream>>>(whh0, qmul0, dmul0);
  rowscale_kernel<<<16, 256, 0, stream>>>(whh1, qmul1, dmul1);
  wq8_kernel<<<256, 256, 0, stream>>>(whh0, qmul0, wq0);
  wq8_kernel<<<256, 256, 0, stream>>>(whh1, qmul1, wq1);

  // layer 0: xg0 = x @ w_ih0^T + (b_ih0 + b_hh0)
  gemm_bt_kernel<0><<<dim3(8, 256), 256, 0, stream>>>(x_h, wih0_h, bsum0, xg, 32768, 1024, 768);
  lstm_rec_kernel<<<64, 512, 0, stream>>>(xg, (const u32x4*)wq0, dmul0, h1, 512);
  // layer 1
  gemm_bt_kernel<0><<<dim3(8, 256), 256, 0, stream>>>(h1, wih1_h, bsum1, xg, 32768, 1024, 256);
  lstm_rec_kernel<<<64, 512, 0, stream>>>(xg, (const u32x4*)wq1, dmul1, h2, 512);
  // LN + attention pooling
  ln_attn_kernel<<<64, 256, 0, stream>>>(h2, lnw, lnb, aw, att_h);
  // FC: out = attended @ fc_w^T + fc_b  (fp32 out)
  gemm_bt_kernel<1><<<dim3(239, 1), 256, 0, stream>>>(att_h, fcw_h, fcb, d_out, 64, 30522, 256);
}

// Round 9
// 1759.209 us; speedup vs baseline: 8.0560x; 1.2576x over previous
//
#include <hip/hip_runtime.h>
#include <cstdint>

typedef _Float16 f16;
using f16x2 = __attribute__((ext_vector_type(2))) _Float16;
using f16x4 = __attribute__((ext_vector_type(4))) _Float16;
using f16x8 = __attribute__((ext_vector_type(8))) _Float16;
using f32x4 = __attribute__((ext_vector_type(4))) float;
using u32x4 = __attribute__((ext_vector_type(4))) uint32_t;
using i32x4 = __attribute__((ext_vector_type(4))) int;

// Newton-refined reciprocal: v_rcp_f32 + 1 NR step -> <=1 ulp (IEEE-equivalent
// for our purposes) at ~4 VALU ops instead of ~15 for the IEEE divide expansion.
__device__ __forceinline__ float rcp_nr(float x) {
  float r = __builtin_amdgcn_rcpf(x);
  return fmaf(fmaf(-x, r, 1.0f), r, r);
}
__device__ __forceinline__ float sigmoidf_(float x) {
  float e = exp2f(-x * 1.44269504088896f);
  return rcp_nr(1.0f + e);
}
__device__ __forceinline__ float tanhf_(float x) {
  float e = exp2f(x * 2.88539008177793f);   // exp(2x)
  return 1.0f - 2.0f * rcp_nr(e + 1.0f);
}

// i8 MFMA, B operand + accumulator pinned in AGPR (zero-move weight reads).
__device__ __forceinline__ void mfma_i8(i32x4& d, u32x4 a, u32x4 b) {
  asm("v_mfma_i32_16x16x64_i8 %0, %1, %2, %0"
      : "+a"(d)
      : "v"(a), "a"(b));
}

// ---------------- conversion / prep kernels ----------------

__global__ void f32_to_f16_kernel(const float* __restrict__ in, f16* __restrict__ out, long n4) {
  long stride = (long)gridDim.x * blockDim.x;
  for (long i = blockIdx.x * (long)blockDim.x + threadIdx.x; i < n4; i += stride) {
    f32x4 v = *(const f32x4*)(in + i * 4);
    f16x4 h;
    h[0] = (f16)v[0]; h[1] = (f16)v[1]; h[2] = (f16)v[2]; h[3] = (f16)v[3];
    *(f16x4*)(out + i * 4) = h;
  }
}

__global__ void addvec_kernel(const float* __restrict__ a, const float* __restrict__ b,
                              float* __restrict__ o, int n) {
  int i = blockIdx.x * blockDim.x + threadIdx.x;
  if (i < n) o[i] = a[i] + b[i];
}

// Per-gate-row symmetric int8 scales: qmul[r]=127/max|W_r|, dmul[r]=max|W_r|/127^2.
__global__ __launch_bounds__(256) void rowscale_kernel(const float* __restrict__ whh,
                                                       float* __restrict__ qmul,
                                                       float* __restrict__ dmul) {
  const int wv = (blockIdx.x * 256 + threadIdx.x) >> 6;  // global wave 0..63
  const int lane = threadIdx.x & 63;
  for (int rr = 0; rr < 16; ++rr) {
    int r = wv * 16 + rr;
    f32x4 v = *(const f32x4*)(whh + r * 256 + lane * 4);
    float m = fmaxf(fmaxf(fabsf(v[0]), fabsf(v[1])), fmaxf(fabsf(v[2]), fabsf(v[3])));
#pragma unroll
    for (int s = 1; s < 64; s <<= 1) m = fmaxf(m, __shfl_xor(m, s, 64));
    if (lane == 0) {
      float sr = fmaxf(m, 1e-8f);
      qmul[r] = 127.0f / sr;
      dmul[r] = sr / 16129.0f;
    }
  }
}

// int8 B-fragment prep for v_mfma_i32_16x16x64_i8.
// dword i = ((t*4 + c)*64 + l)*4 + d ; byte e of dword holds
// Wq[r = t*16 + (l&15)][k = c*64 + ((l>>4)&3)*16 + d*4 + e].
// (A-side h8 packing uses the same (lane,byte)->k map; contraction is
// invariant to the shared permutation, so this is correct by construction.)
__global__ void wq8_kernel(const float* __restrict__ whh, const float* __restrict__ qmul,
                           uint32_t* __restrict__ wq) {
  int i = blockIdx.x * blockDim.x + threadIdx.x;  // 65536 threads
  int d = i & 3, l = (i >> 2) & 63, c = (i >> 8) & 3, t = i >> 10;
  int r = t * 16 + (l & 15);
  int k0 = c * 64 + ((l >> 4) & 3) * 16 + d * 4;
  float qm = qmul[r];
  uint32_t out = 0;
#pragma unroll
  for (int e = 0; e < 4; ++e) {
    int q = __float2int_rn(whh[r * 256 + k0 + e] * qm);
    q = min(127, max(-127, q));
    out |= ((uint32_t)(uint8_t)(int8_t)q) << (8 * e);
  }
  wq[i] = out;
}

// ---------------- GEMM: C[m,n] = sum_k A[m,k]*B[n,k] + bias[n] ----------------
// A [M,K] f16 row-major, B [N,K] f16 row-major. 128x128 tile, BK=32, 256 thr.

template <int OUTF32>
__global__ __launch_bounds__(256) void gemm_bt_kernel(
    const f16* __restrict__ A, const f16* __restrict__ B,
    const float* __restrict__ bias, void* __restrict__ Cout,
    int M, int N, int K) {
  __shared__ __align__(16) f16 Al[128 * 32];
  __shared__ __align__(16) f16 Bl[128 * 32];
  const int tid = threadIdx.x;
  const int lane = tid & 63, wave = tid >> 6;
  const int bn = blockIdx.x, bm = blockIdx.y;
  const int qm = (wave >> 1) * 64, qn = (wave & 1) * 64;

  f32x4 acc[4][4];
#pragma unroll
  for (int i = 0; i < 4; ++i)
#pragma unroll
    for (int j = 0; j < 4; ++j) acc[i][j] = (f32x4){0.f, 0.f, 0.f, 0.f};

  const int c0 = tid, c1 = 256 + tid;
  const int row0 = c0 >> 2, off0 = c0 & 3;
  const int row1 = c1 >> 2, off1 = c1 & 3;
  const int gmA0 = min(bm * 128 + row0, M - 1);
  const int gmA1 = min(bm * 128 + row1, M - 1);
  const int gnB0 = min(bn * 128 + row0, N - 1);
  const int gnB1 = min(bn * 128 + row1, N - 1);

  for (int k0 = 0; k0 < K; k0 += 32) {
    u32x4 ar0 = *(const u32x4*)(A + (size_t)gmA0 * K + k0 + off0 * 8);
    u32x4 ar1 = *(const u32x4*)(A + (size_t)gmA1 * K + k0 + off1 * 8);
    u32x4 br0 = *(const u32x4*)(B + (size_t)gnB0 * K + k0 + off0 * 8);
    u32x4 br1 = *(const u32x4*)(B + (size_t)gnB1 * K + k0 + off1 * 8);
    __syncthreads();  // previous iteration's LDS reads done
    *(u32x4*)&Al[c0 * 8] = ar0;
    *(u32x4*)&Al[c1 * 8] = ar1;
    *(u32x4*)&Bl[c0 * 8] = br0;
    *(u32x4*)&Bl[c1 * 8] = br1;
    __syncthreads();
    f16x8 af[4], bf[4];
#pragma unroll
    for (int mt = 0; mt < 4; ++mt)
      af[mt] = *(const f16x8*)&Al[(qm + mt * 16 + (lane & 15)) * 32 + (lane >> 4) * 8];
#pragma unroll
    for (int nt = 0; nt < 4; ++nt)
      bf[nt] = *(const f16x8*)&Bl[(qn + nt * 16 + (lane & 15)) * 32 + (lane >> 4) * 8];
#pragma unroll
    for (int mt = 0; mt < 4; ++mt)
#pragma unroll
      for (int nt = 0; nt < 4; ++nt)
        acc[mt][nt] = __builtin_amdgcn_mfma_f32_16x16x32_f16(af[mt], bf[nt], acc[mt][nt], 0, 0, 0);
  }

#pragma unroll
  for (int mt = 0; mt < 4; ++mt)
#pragma unroll
    for (int nt = 0; nt < 4; ++nt)
#pragma unroll
      for (int j = 0; j < 4; ++j) {
        int gm = bm * 128 + qm + mt * 16 + (lane >> 4) * 4 + j;
        int gn = bn * 128 + qn + nt * 16 + (lane & 15);
        if (gm < M && gn < N) {
          float v = acc[mt][nt][j] + bias[gn];
          if (OUTF32)
            ((float*)Cout)[(size_t)gm * N + gn] = v;
          else
            ((f16*)Cout)[(size_t)gm * N + gn] = (f16)v;
        }
      }
}

// ---------------- persistent LSTM recurrence (int8 MFMA, two-level h) ----------------
// PROVEN R7 GEOMETRY (passed, absmax 0.0098): 64 blocks x 512 threads (8 waves),
// __launch_bounds__(512,2). 8 weight tiles/wave in AGPR (128 regs + 32 acc = 160,
// safely under the 256 architectural a-register names — R8's 320-a-reg layout failed).
// Two-level h: A row0 = h_hi (int8, h*127), row1 = h_lo (residual); same MFMA yields
// D row0 = Wq.h_hi, D row1 = Wq.h_lo; gate = dmul*D0 + (dmul/127)*D1 + xg.
// R9 deltas vs R7 (perf-only, numerics-identical):
//   1. next-step xg prefetch (xc regs) — hides L3 latency under the MFMA phase.
//   2. NR-refined rcp in activations — cuts ~5 IEEE divides/unit to rcp+2fma.

__global__ __launch_bounds__(512, 2) void lstm_rec_kernel(
    const f16* __restrict__ xg,          // [B*T, 1024], biases included
    const u32x4* __restrict__ wq,        // [64 t][4 c][64 l] u32x4 int8 frags
    const float* __restrict__ dmul,      // [1024] per-row dequant scale
    f16* __restrict__ h_out,             // [B*T, 256]
    int T) {
  __shared__ __align__(16) uint8_t h8[2][512];   // [hi 256 | lo 256], double-buffered
  const int b = blockIdx.x;
  const int tid = threadIdx.x;
  const int w = tid >> 6, lane = tid & 63;
  const int l15 = lane & 15, kg = (lane >> 4) & 3;
  const int base = w * 16 + l15;        // row(j) = base + 128*j ; uA=base, uB=base+128
  const int uA = base, uB = base + 128;
  const int asel = (l15 == 1) ? 256 : 0;  // row1 lanes read the lo slice

  // all 8 tiles -> AGPR (used only via "a" asm operands)
  u32x4 wt[8][4];
#pragma unroll
  for (int j = 0; j < 8; ++j)
#pragma unroll
    for (int c = 0; c < 4; ++c)
      wt[j][c] = wq[((w + 8 * j) * 4 + c) * 64 + lane];
  float sc[8], sc2[8];
#pragma unroll
  for (int j = 0; j < 8; ++j) {
    sc[j] = dmul[base + 128 * j];
    sc2[j] = sc[j] * (1.0f / 127.0f);
  }

  if (tid < 256) ((uint32_t*)h8)[tid] = 0;   // zero both buffers (1 KB)
  float cA = 0.f, cB = 0.f;
  __syncthreads();

  const f16* xt = xg + (size_t)b * T * 1024;
  f16* hob = h_out + (size_t)b * T * 256;

  // prologue: prefetch step-0 xg contributions
  f16 xc[8];
#pragma unroll
  for (int j = 0; j < 8; ++j) xc[j] = xt[base + 128 * j];

  for (int t = 0; t < T; ++t) {
    // consume prefetched xg; issue next step's loads (hidden under this step)
    float xv[8];
#pragma unroll
    for (int j = 0; j < 8; ++j) xv[j] = (float)xc[j];
    const f16* xn = (t + 1 < T) ? xt + 1024 : xt;
#pragma unroll
    for (int j = 0; j < 8; ++j) xc[j] = xn[base + 128 * j];

    i32x4 z = (i32x4){0, 0, 0, 0};
    i32x4 a0 = z, a1 = z, a2 = z, a3 = z, a4 = z, a5 = z, a6 = z, a7 = z;
    const uint8_t* hq = h8[t & 1] + asel;
#pragma unroll
    for (int c = 0; c < 4; ++c) {
      u32x4 afr = *(const u32x4*)(hq + c * 64 + kg * 16);   // row0=hi, row1=lo
      mfma_i8(a0, afr, wt[0][c]);
      mfma_i8(a1, afr, wt[1][c]);
      mfma_i8(a2, afr, wt[2][c]);
      mfma_i8(a3, afr, wt[3][c]);
      mfma_i8(a4, afr, wt[4][c]);
      mfma_i8(a5, afr, wt[5][c]);
      mfma_i8(a6, afr, wt[6][c]);
      mfma_i8(a7, afr, wt[7][c]);
    }
    // dequant + activation (valid on kg=0 lanes; others compute discarded garbage)
    float gI_A = (float)a0[0] * sc[0] + (float)a0[1] * sc2[0] + xv[0];
    float gI_B = (float)a1[0] * sc[1] + (float)a1[1] * sc2[1] + xv[1];
    float gF_A = (float)a2[0] * sc[2] + (float)a2[1] * sc2[2] + xv[2];
    float gF_B = (float)a3[0] * sc[3] + (float)a3[1] * sc2[3] + xv[3];
    float gG_A = (float)a4[0] * sc[4] + (float)a4[1] * sc2[4] + xv[4];
    float gG_B = (float)a5[0] * sc[5] + (float)a5[1] * sc2[5] + xv[5];
    float gO_A = (float)a6[0] * sc[6] + (float)a6[1] * sc2[6] + xv[6];
    float gO_B = (float)a7[0] * sc[7] + (float)a7[1] * sc2[7] + xv[7];
    float iA = sigmoidf_(gI_A), iB = sigmoidf_(gI_B);
    float fA = sigmoidf_(gF_A), fB = sigmoidf_(gF_B);
    float gA = tanhf_(gG_A),   gB = tanhf_(gG_B);
    float oA = sigmoidf_(gO_A), oB = sigmoidf_(gO_B);
    cA = fA * cA + iA * gA;
    cB = fB * cB + iB * gB;
    float hA = oA * tanhf_(cA);
    float hB = oB * tanhf_(cB);
    // two-level quantize: hi = round(h*127); lo = round((h - hi/127)*16129)
    int hiA = __float2int_rn(hA * 127.0f);
    int hiB = __float2int_rn(hB * 127.0f);
    int loA = __float2int_rn(fmaf((float)hiA, -127.0f, hA * 16129.0f));
    int loB = __float2int_rn(fmaf((float)hiB, -127.0f, hB * 16129.0f));
    uint8_t* hn = (uint8_t*)h8[(t + 1) & 1];
    if (lane < 16) {
      hn[uA] = (uint8_t)(int8_t)hiA;
      hn[uB] = (uint8_t)(int8_t)hiB;
      hn[256 + uA] = (uint8_t)(int8_t)loA;
      hn[256 + uB] = (uint8_t)(int8_t)loB;
      hob[(size_t)t * 256 + uA] = (f16)hA;   // global h (vmcnt floats, never drained)
      hob[(size_t)t * 256 + uB] = (f16)hB;
    }
    xt += 1024;
    asm volatile("s_waitcnt lgkmcnt(0)" ::: "memory");  // h8 writes visible
    __builtin_amdgcn_s_barrier();
    __builtin_amdgcn_sched_barrier(0);
  }
}

// ---------------- fused LayerNorm + attention pooling ----------------
// one block per batch, 256 threads.

__global__ __launch_bounds__(256) void ln_attn_kernel(
    const f16* __restrict__ h2, const float* __restrict__ lnw,
    const float* __restrict__ lnb, const float* __restrict__ aw,
    f16* __restrict__ att_out) {
  const int b = blockIdx.x, tid = threadIdx.x;
  const int lane = tid & 63, wave = tid >> 6;
  __shared__ float smu[512], sis[512], ssc[512];
  __shared__ float vbuf[256];
  __shared__ float red[16];

  float vj = aw[tid] * lnw[tid];
  float uj = aw[tid] * lnb[tid];
  vbuf[tid] = vj;
  float rv = vj, ru = uj;
#pragma unroll
  for (int m = 1; m < 64; m <<= 1) { rv += __shfl_xor(rv, m, 64); ru += __shfl_xor(ru, m, 64); }
  if (lane == 0) { red[wave] = rv; red[4 + wave] = ru; }
  __syncthreads();
  const float Vsum = red[0] + red[1] + red[2] + red[3];
  const float Csum = red[4] + red[5] + red[6] + red[7];
  const f32x4 v4 = *(const f32x4*)&vbuf[lane * 4];
  const f16* hb = h2 + (size_t)b * 512 * 256;

  for (int tt = wave; tt < 512; tt += 4) {
    f16x4 hv = *(const f16x4*)(hb + (size_t)tt * 256 + lane * 4);
    float h0 = (float)hv[0], h1 = (float)hv[1], h2v = (float)hv[2], h3 = (float)hv[3];
    float s1 = h0 + h1 + h2v + h3;
    float s2 = h0 * h0 + h1 * h1 + h2v * h2v + h3 * h3;
    float sv = h0 * v4[0] + h1 * v4[1] + h2v * v4[2] + h3 * v4[3];
#pragma unroll
    for (int m = 1; m < 64; m <<= 1) {
      s1 += __shfl_xor(s1, m, 64);
      s2 += __shfl_xor(s2, m, 64);
      sv += __shfl_xor(sv, m, 64);
    }
    if (lane == 0) {
      float mu = s1 * (1.0f / 256.0f);
      float var = s2 * (1.0f / 256.0f) - mu * mu;
      float is = rsqrtf(var + 1e-5f);
      smu[tt] = mu; sis[tt] = is;
      ssc[tt] = (sv - mu * Vsum) * is + Csum;
    }
  }
  __syncthreads();
  // softmax over 512 scores
  float a0 = ssc[tid], a1 = ssc[tid + 256];
  float mx = fmaxf(a0, a1);
#pragma unroll
  for (int m = 1; m < 64; m <<= 1) mx = fmaxf(mx, __shfl_xor(mx, m, 64));
  if (lane == 0) red[wave] = mx;
  __syncthreads();
  mx = fmaxf(fmaxf(red[0], red[1]), fmaxf(red[2], red[3]));
  __syncthreads();  // protect red reuse
  float p0 = exp2f((a0 - mx) * 1.44269504f);
  float p1 = exp2f((a1 - mx) * 1.44269504f);
  float ps = p0 + p1;
  float pm = p0 * smu[tid] * sis[tid] + p1 * smu[tid + 256] * sis[tid + 256];
#pragma unroll
  for (int m = 1; m < 64; m <<= 1) { ps += __shfl_xor(ps, m, 64); pm += __shfl_xor(pm, m, 64); }
  if (lane == 0) { red[wave] = ps; red[8 + wave] = pm; }
  __syncthreads();
  const float S = red[0] + red[1] + red[2] + red[3];
  const float PM = (red[8] + red[9] + red[10] + red[11]) / S;
  ssc[tid] = p0 / S * sis[tid];          // alpha_t
  ssc[tid + 256] = p1 / S * sis[tid + 256];
  __syncthreads();
  // pass 2: attended_j = lnw_j*(sum_t alpha_t h_tj - PM) + lnb_j
  float acc = 0.f;
  for (int t = 0; t < 512; ++t) acc += ssc[t] * (float)hb[(size_t)t * 256 + tid];
  float att = lnw[tid] * (acc - PM) + lnb[tid];
  att_out[b * 256 + tid] = (f16)att;
}

// ---------------- launch ----------------

extern "C" void kernel_launch(void* const* d_in, const int* in_sizes, int n_in,
                              void* d_out, int out_size, void* d_ws, size_t ws_size,
                              hipStream_t stream) {
  (void)in_sizes; (void)n_in; (void)out_size; (void)ws_size;
  const float* x    = (const float*)d_in[0];
  const float* wih0 = (const float*)d_in[1];
  const float* whh0 = (const float*)d_in[2];
  const float* bih0 = (const float*)d_in[3];
  const float* bhh0 = (const float*)d_in[4];
  const float* wih1 = (const float*)d_in[5];
  const float* whh1 = (const float*)d_in[6];
  const float* bih1 = (const float*)d_in[7];
  const float* bhh1 = (const float*)d_in[8];
  const float* lnw  = (const float*)d_in[9];
  const float* lnb  = (const float*)d_in[10];
  const float* aw   = (const float*)d_in[11];
  const float* fcw  = (const float*)d_in[12];
  const float* fcb  = (const float*)d_in[13];

  char* ws = (char*)d_ws;
  f16* x_h      = (f16*)(ws + 0);            // 50331648 B; region reused after GEMM0:
  f16* h1       = (f16*)(ws + 0);            //   h1: 16777216 B
  f16* h2       = (f16*)(ws + 16777216);     //   h2: 16777216 B
  f16* wih0_h   = (f16*)(ws + 50331648);     // 1572864
  f16* wih1_h   = (f16*)(ws + 51904512);     // 524288
  f16* fcw_h    = (f16*)(ws + 52428800);     // 15627264
  uint32_t* wq0 = (uint32_t*)(ws + 68056064);// 262144
  uint32_t* wq1 = (uint32_t*)(ws + 68318208);// 262144
  float* qmul0  = (float*)(ws + 68580352);   // 4096
  float* dmul0  = (float*)(ws + 68584448);   // 4096
  float* qmul1  = (float*)(ws + 68588544);   // 4096
  float* dmul1  = (float*)(ws + 68592640);   // 4096
  float* bsum0  = (float*)(ws + 69104640);   // 4096
  float* bsum1  = (float*)(ws + 69108736);   // 4096
  f16* att_h    = (f16*)(ws + 69112832);     // 32768
  f16* xg       = (f16*)(ws + 69145600);     // 67108864 (shared by both layers)

  f32_to_f16_kernel<<<4096, 256, 0, stream>>>(x, x_h, 25165824 / 4);
  f32_to_f16_kernel<<<768, 256, 0, stream>>>(wih0, wih0_h, 786432 / 4);
  f32_to_f16_kernel<<<256, 256, 0, stream>>>(wih1, wih1_h, 262144 / 4);
  f32_to_f16_kernel<<<2048, 256, 0, stream>>>(fcw, fcw_h, 7813632 / 4);
  addvec_kernel<<<4, 256, 0, stream>>>(bih0, bhh0, bsum0, 1024);
  addvec_kernel<<<4, 256, 0, stream>>>(bih1, bhh1, bsum1, 1024);
  rowscale_kernel<<<16, 256, 0, stream>>>(whh0, qmul0, dmul0);
  rowscale_kernel<<<16, 256, 0, stream>>>(whh1, qmul1, dmul1);
  wq8_kernel<<<256, 256, 0, stream>>>(whh0, qmul0, wq0);
  wq8_kernel<<<256, 256, 0, stream>>>(whh1, qmul1, wq1);

  // layer 0: xg0 = x @ w_ih0^T + (b_ih0 + b_hh0)
  gemm_bt_kernel<0><<<dim3(8, 256), 256, 0, stream>>>(x_h, wih0_h, bsum0, xg, 32768, 1024, 768);
  lstm_rec_kernel<<<64, 512, 0, stream>>>(xg, (const u32x4*)wq0, dmul0, h1, 512);
  // layer 1
  gemm_bt_kernel<0><<<dim3(8, 256), 256, 0, stream>>>(h1, wih1_h, bsum1, xg, 32768, 1024, 256);
  lstm_rec_kernel<<<64, 512, 0, stream>>>(xg, (const u32x4*)wq1, dmul1, h2, 512);
  // LN + attention pooling
  ln_attn_kernel<<<64, 256, 0, stream>>>(h2, lnw, lnb, aw, att_h);
  // FC: out = attended @ fc_w^T + fc_b  (fp32 out)
  gemm_bt_kernel<1><<<dim3(239, 1), 256, 0, stream>>>(att_h, fcw_h, fcb, d_out, 64, 30522, 256);
}